// Round 1
// baseline (663.400 us; speedup 1.0000x reference)
//
#include <hip/hip_runtime.h>

typedef __attribute__((ext_vector_type(8))) short short8;
typedef __attribute__((ext_vector_type(4))) float floatx4;

#define NHID 128
#define PADROW 136   // 128 + 8 bf16 pad: LDS row stride 272B -> 16B-aligned b128, 2-way banks (free)
#define EB 64        // edges (or nodes) per batch

__device__ __forceinline__ unsigned short f2bf(float x) {
  unsigned int u = __float_as_uint(x);
  u += 0x7FFFu + ((u >> 16) & 1u);          // RNE
  return (unsigned short)(u >> 16);
}

__device__ __forceinline__ unsigned int pack2(float a, float b) {
  return (unsigned int)f2bf(a) | ((unsigned int)f2bf(b) << 16);
}

// Load the 32 loop-invariant B-fragments (mfma_f32_16x16x32_bf16) of a
// 128x128 row-major f32 weight matrix into registers.
// B[k][n]: lane holds n = 16*nt + (lane&15), k = 32*kc + (lane>>4)*8 + j.
__device__ __forceinline__ void load_bfrags(const float* __restrict__ wmat,
                                            short8* bf, int m, int q) {
  #pragma unroll
  for (int kc = 0; kc < 4; ++kc) {
    #pragma unroll
    for (int nt = 0; nt < 8; ++nt) {
      short8 v;
      #pragma unroll
      for (int j = 0; j < 8; ++j) {
        v[j] = (short)f2bf(wmat[(kc * 32 + q * 8 + j) * NHID + nt * 16 + m]);
      }
      bf[kc * 8 + nt] = v;
    }
  }
}

// MFMA: C[64 x 128] += A(LDS uA) * B(regs). Wave w owns rows 16w..16w+15.
__device__ __forceinline__ void mfma_block(const unsigned short* uA,
                                           const short8* bf, floatx4* acc,
                                           int w, int m, int q) {
  #pragma unroll
  for (int kc = 0; kc < 4; ++kc) {
    short8 a = *(const short8*)(uA + (16 * w + m) * PADROW + kc * 32 + q * 8);
    #pragma unroll
    for (int nt = 0; nt < 8; ++nt)
      acc[nt] = __builtin_amdgcn_mfma_f32_16x16x32_bf16(a, bf[kc * 8 + nt],
                                                        acc[nt], 0, 0, 0);
  }
}

// edge_index dtype probe: if input is int64, every odd int32 slot (high word)
// is 0; if int32, odd slots are random node ids (P(all 64 == 0) ~ 1e-320).
__global__ void detect_kernel(const int* __restrict__ ei, int* __restrict__ flag) {
  unsigned long long b = __ballot(ei[2 * threadIdx.x + 1] != 0);
  if (threadIdx.x == 0) flag[0] = (b == 0ULL) ? 1 : 0;
}

__global__ void zero_kernel(float4* __restrict__ p, int n4) {
  int i = blockIdx.x * blockDim.x + threadIdx.x;
  int stride = gridDim.x * blockDim.x;
  float4 z = make_float4(0.f, 0.f, 0.f, 0.f);
  for (; i < n4; i += stride) p[i] = z;
}

// Edge MLP fused with segment-max: u = relu([xi, xj-xi]@w1 + b1) (VALU, fp32),
// h = u@w2 + b2 (bf16 MFMA), atomicMax(agg[dst], h) for h > 0.
__global__ __launch_bounds__(256, 2) void edge_kernel(
    const float* __restrict__ x, const int* __restrict__ ei,
    const float* __restrict__ w1, const float* __restrict__ b1,
    const float* __restrict__ w2, const float* __restrict__ b2,
    float* agg, const int* __restrict__ flag64, int N, int E) {
  __shared__ unsigned short uA[EB * PADROW];
  __shared__ float w1s[6 * NHID];
  __shared__ float b1s[NHID], b2s[NHID];
  __shared__ int es[EB], ed[EB];

  const int t = threadIdx.x;
  const int lane = t & 63;
  const int w = t >> 6;
  const int m = lane & 15;
  const int q = lane >> 4;

  for (int i = t; i < 6 * NHID; i += 256) w1s[i] = w1[i];
  if (t < NHID) { b1s[t] = b1[t]; b2s[t] = b2[t]; }

  short8 bf[32];
  load_bfrags(w2, bf, m, q);

  const bool is64 = (flag64[0] != 0);
  const int nb = (E + EB - 1) / EB;

  for (int batch = blockIdx.x; batch < nb; batch += gridDim.x) {
    const int gbase = batch * EB;
    if (t < EB) {
      int e = gbase + t;
      es[t] = (e < E) ? (is64 ? ei[2 * e] : ei[e]) : 0;
    } else if (t < 2 * EB) {
      int tt = t - EB;
      int e = gbase + tt;
      ed[tt] = (e < E) ? (is64 ? ei[2 * E + 2 * e] : ei[E + e]) : 0;
    }
    __syncthreads();

    // stage 1: layer 1 -> bf16 uA. thread t: edge t>>2, 32 hidden units.
    {
      const int e = t >> 2;
      const int c0 = (t & 3) * 32;
      const int si = es[e], di = ed[e];
      float xi0 = x[di * 3], xi1 = x[di * 3 + 1], xi2 = x[di * 3 + 2];
      float msg[6];
      msg[0] = xi0; msg[1] = xi1; msg[2] = xi2;
      msg[3] = x[si * 3] - xi0; msg[4] = x[si * 3 + 1] - xi1; msg[5] = x[si * 3 + 2] - xi2;
      unsigned int* d32 = (unsigned int*)uA;
      const int base32 = (e * PADROW + c0) >> 1;
      #pragma unroll
      for (int cc = 0; cc < 32; cc += 2) {
        float u0 = b1s[c0 + cc], u1 = b1s[c0 + cc + 1];
        #pragma unroll
        for (int d = 0; d < 6; ++d) {
          u0 += msg[d] * w1s[d * NHID + c0 + cc];
          u1 += msg[d] * w1s[d * NHID + c0 + cc + 1];
        }
        d32[base32 + (cc >> 1)] = pack2(fmaxf(u0, 0.f), fmaxf(u1, 0.f));
      }
    }
    __syncthreads();

    // stage 2: h = u @ w2
    floatx4 acc[8];
    #pragma unroll
    for (int nt = 0; nt < 8; ++nt) { floatx4 z = {0.f, 0.f, 0.f, 0.f}; acc[nt] = z; }
    mfma_block(uA, bf, acc, w, m, q);

    // stage 3: + b2, atomicMax into agg. D: row=(q*4+r), col=16*nt+m.
    #pragma unroll
    for (int nt = 0; nt < 8; ++nt) {
      const int c = nt * 16 + m;
      const float bb = b2s[c];
      #pragma unroll
      for (int r = 0; r < 4; ++r) {
        const int erow = 16 * w + q * 4 + r;
        if (gbase + erow < E) {
          float hb = acc[nt][r] + bb;
          if (hb > 0.f)
            atomicMax((unsigned int*)(agg + (size_t)ed[erow] * NHID + c),
                      __float_as_uint(hb));
        }
      }
    }
    __syncthreads();  // protect es/ed + uA before next iteration
  }
}

// enc = agg @ w3 + b3, written in-place over agg (block owns its 64 rows).
// relu(agg) is identity: agg >= 0 by construction.
__global__ __launch_bounds__(256, 2) void enc_kernel(
    const float* __restrict__ w3, const float* __restrict__ b3,
    float* agg, int N) {
  __shared__ unsigned short uA[EB * PADROW];
  __shared__ float b3s[NHID];

  const int t = threadIdx.x;
  const int lane = t & 63;
  const int w = t >> 6;
  const int m = lane & 15;
  const int q = lane >> 4;

  if (t < NHID) b3s[t] = b3[t];
  short8 bf[32];
  load_bfrags(w3, bf, m, q);

  const int nb = (N + EB - 1) / EB;
  for (int batch = blockIdx.x; batch < nb; batch += gridDim.x) {
    const int base = batch * EB;
    __syncthreads();
    // stage 1: coalesced float4 copy agg rows -> bf16 uA
    for (int i = t; i < EB * 32; i += 256) {
      const int row = i >> 5, c4 = i & 31;
      const int node = base + row;
      float4 v = make_float4(0.f, 0.f, 0.f, 0.f);
      if (node < N) v = ((const float4*)agg)[(size_t)node * 32 + c4];
      unsigned int* d32 = (unsigned int*)uA;
      const int o = row * (PADROW >> 1) + c4 * 2;
      d32[o] = pack2(v.x, v.y);
      d32[o + 1] = pack2(v.z, v.w);
    }
    __syncthreads();

    floatx4 acc[8];
    #pragma unroll
    for (int nt = 0; nt < 8; ++nt) { floatx4 z = {0.f, 0.f, 0.f, 0.f}; acc[nt] = z; }
    mfma_block(uA, bf, acc, w, m, q);

    #pragma unroll
    for (int nt = 0; nt < 8; ++nt) {
      const int c = nt * 16 + m;
      const float bb = b3s[c];
      #pragma unroll
      for (int r = 0; r < 4; ++r) {
        const int node = base + 16 * w + q * 4 + r;
        if (node < N) agg[(size_t)node * NHID + c] = acc[nt][r] + bb;
      }
    }
  }
}

// t = relu(enc @ w4 + b4); dec = t @ w5 + b5; out = pos + 0.1*tanh(dec)
__global__ __launch_bounds__(256, 2) void dec_kernel(
    const float* __restrict__ w4, const float* __restrict__ b4,
    const float* __restrict__ w5, const float* __restrict__ b5,
    const float* __restrict__ pos, const float* __restrict__ enc,
    float* __restrict__ out, int N) {
  __shared__ unsigned short uA[EB * PADROW];
  __shared__ float b4s[NHID];
  __shared__ float w5s[NHID * 3];

  const int t = threadIdx.x;
  const int lane = t & 63;
  const int w = t >> 6;
  const int m = lane & 15;
  const int q = lane >> 4;

  if (t < NHID) b4s[t] = b4[t];
  for (int i = t; i < NHID * 3; i += 256) w5s[i] = w5[i];
  short8 bf[32];
  load_bfrags(w4, bf, m, q);

  const int nb = (N + EB - 1) / EB;
  for (int batch = blockIdx.x; batch < nb; batch += gridDim.x) {
    const int base = batch * EB;
    __syncthreads();
    for (int i = t; i < EB * 32; i += 256) {
      const int row = i >> 5, c4 = i & 31;
      const int node = base + row;
      float4 v = make_float4(0.f, 0.f, 0.f, 0.f);
      if (node < N) v = ((const float4*)enc)[(size_t)node * 32 + c4];
      unsigned int* d32 = (unsigned int*)uA;
      const int o = row * (PADROW >> 1) + c4 * 2;
      d32[o] = pack2(v.x, v.y);
      d32[o + 1] = pack2(v.z, v.w);
    }
    __syncthreads();

    floatx4 acc[8];
    #pragma unroll
    for (int nt = 0; nt < 8; ++nt) { floatx4 z = {0.f, 0.f, 0.f, 0.f}; acc[nt] = z; }
    mfma_block(uA, bf, acc, w, m, q);

    // epilogue: t = relu(acc + b4), partial dec[j] = sum_c t*w5[c][j]
    float p[4][3];
    #pragma unroll
    for (int r = 0; r < 4; ++r) { p[r][0] = 0.f; p[r][1] = 0.f; p[r][2] = 0.f; }
    #pragma unroll
    for (int nt = 0; nt < 8; ++nt) {
      const int c = nt * 16 + m;
      const float bb = b4s[c];
      const float w50 = w5s[c * 3], w51 = w5s[c * 3 + 1], w52 = w5s[c * 3 + 2];
      #pragma unroll
      for (int r = 0; r < 4; ++r) {
        float tv = fmaxf(acc[nt][r] + bb, 0.f);
        p[r][0] += tv * w50; p[r][1] += tv * w51; p[r][2] += tv * w52;
      }
    }
    // reduce over the 16 lanes (m) of each quad
    #pragma unroll
    for (int off = 8; off >= 1; off >>= 1) {
      #pragma unroll
      for (int r = 0; r < 4; ++r) {
        p[r][0] += __shfl_xor(p[r][0], off, 16);
        p[r][1] += __shfl_xor(p[r][1], off, 16);
        p[r][2] += __shfl_xor(p[r][2], off, 16);
      }
    }
    if (m == 0) {
      #pragma unroll
      for (int r = 0; r < 4; ++r) {
        const int node = base + 16 * w + q * 4 + r;
        if (node < N) {
          #pragma unroll
          for (int j = 0; j < 3; ++j) {
            float dec = p[r][j] + b5[j];
            out[node * 3 + j] = pos[node * 3 + j] + 0.1f * tanhf(dec);
          }
        }
      }
    }
  }
}

extern "C" void kernel_launch(void* const* d_in, const int* in_sizes, int n_in,
                              void* d_out, int out_size, void* d_ws, size_t ws_size,
                              hipStream_t stream) {
  const float* x   = (const float*)d_in[0];
  const float* pos = (const float*)d_in[1];
  const int*   ei  = (const int*)d_in[2];
  const float* w1  = (const float*)d_in[3];
  const float* b1  = (const float*)d_in[4];
  const float* w2  = (const float*)d_in[5];
  const float* b2  = (const float*)d_in[6];
  const float* w3  = (const float*)d_in[7];
  const float* b3  = (const float*)d_in[8];
  const float* w4  = (const float*)d_in[9];
  const float* b4  = (const float*)d_in[10];
  const float* w5  = (const float*)d_in[11];
  const float* b5  = (const float*)d_in[12];
  float* out = (float*)d_out;

  const int N = in_sizes[0] / 3;
  const int E = in_sizes[2] / 2;

  float* agg = (float*)d_ws;                                   // N*128 f32 = 51.2 MB
  int* flag  = (int*)((char*)d_ws + (size_t)N * NHID * sizeof(float));

  detect_kernel<<<1, 64, 0, stream>>>(ei, flag);
  zero_kernel<<<2048, 256, 0, stream>>>((float4*)agg, N * NHID / 4);
  edge_kernel<<<512, 256, 0, stream>>>(x, ei, w1, b1, w2, b2, agg, flag, N, E);
  enc_kernel<<<512, 256, 0, stream>>>(w3, b3, agg, N);
  dec_kernel<<<512, 256, 0, stream>>>(w4, b4, w5, b5, pos, agg, out, N);
}